// Round 1
// baseline (350.498 us; speedup 1.0000x reference)
//
#include <hip/hip_runtime.h>
#include <math.h>

// Problem constants (fixed by setup_inputs)
#define B_    2
#define L_    4096
#define H_    8
#define D_    64
#define S_    45      // sample_k
#define NT_   45      // n_top
#define BH_   16      // B*H
#define CHV   128     // cumsum chunk length
#define NCHV  32      // L_/CHV
#define KC    128     // attention key-chunk length
#define NKC   32      // L_/KC
#define SCALE 0.125f  // 1/sqrt(64)
#define NEG_BIG (-1e30f)

// Workspace layout (float element offsets; ints share the same 4B slots)
#define OFF_M     0         // 65536 floats: M[bh][q]
#define OFF_VSUM  65536     // 32768 floats: vsum[bh][ch][d]
#define OFF_MTOP  98304     // 720 ints:    M_top[bh][u]
#define OFF_MPART 99072     // 23040 floats: m partial [bh][kc][u]
#define OFF_SPART 122112    // 23040 floats: sumexp partial
#define OFF_CTXP  145152    // 1474560 floats: ctx partial [bh][kc][u][d]

// ---------------------------------------------------------------------------
// Kernel A: part 1 (blocks < 16384): M[b,h,q] = max_s dot - sum_s dot / L
//           part 2 (blocks >= 16384): per-chunk V sums for the cumsum
// ---------------------------------------------------------------------------
__global__ __launch_bounds__(256) void kA(const float* __restrict__ Q,
                                          const float* __restrict__ Kt,
                                          const float* __restrict__ V,
                                          const int* __restrict__ samp,
                                          float* __restrict__ ws)
{
    int tid  = threadIdx.x;
    int w    = tid >> 6;
    int lane = tid & 63;

    if (blockIdx.x < 16384) {
        // wave per (bh, q); lane = sample index s (lanes 45..63 masked)
        int widx = blockIdx.x * 4 + w;
        int bh = widx >> 12, q = widx & 4095;
        int b = bh >> 3, h = bh & 7;
        int s = lane;
        int idx = samp[q * S_ + (s < S_ ? s : 0)];

        const float4* kp = (const float4*)(Kt + ((((long)b * L_ + idx) * H_ + h) << 6));
        const float4* qp = (const float4*)(Q  + ((((long)b * L_ + q  ) * H_ + h) << 6));
        float acc = 0.f;
#pragma unroll
        for (int j = 0; j < 16; ++j) {
            float4 kv = kp[j];
            float4 qv = qp[j];   // broadcast across lanes (L1 hit)
            acc += qv.x * kv.x + qv.y * kv.y + qv.z * kv.z + qv.w * kv.w;
        }
        float mx = (s < S_) ? acc : NEG_BIG;
        float sm = (s < S_) ? acc : 0.f;
#pragma unroll
        for (int off = 32; off; off >>= 1) {
            mx = fmaxf(mx, __shfl_xor(mx, off));
            sm += __shfl_xor(sm, off);
        }
        if (lane == 0)
            ws[OFF_M + bh * L_ + q] = mx - sm * (1.0f / (float)L_);
    } else {
        // wave per (bh, ch): vsum[bh][ch][d] = sum_{i<CHV} V[b, ch*CHV+i, h, d]
        int unit = (blockIdx.x - 16384) * 4 + w;   // 0..511
        int bh = unit >> 5, ch = unit & 31;
        int b = bh >> 3, h = bh & 7;
        int d = lane;
        const float* vp = V + ((((long)b * L_ + (long)ch * CHV) * H_ + h) << 6) + d;
        float ssum = 0.f;
        for (int i = 0; i < CHV; ++i) ssum += vp[(long)i * (H_ * D_)];
        ws[OFF_VSUM + unit * 64 + d] = ssum;
    }
}

// ---------------------------------------------------------------------------
// Kernel B: part 1 (blocks < 16): top-45 of M per (b,h) (iterative argmax,
//           lowest-index tie-break to match jax.lax.top_k)
//           part 2 (blocks >= 16): cumsum write: out = prefix-sum of V
// ---------------------------------------------------------------------------
__global__ __launch_bounds__(256) void kB(const float* __restrict__ V,
                                          float* __restrict__ out,
                                          float* __restrict__ ws)
{
    int tid = threadIdx.x;

    if (blockIdx.x < 16) {
        int bh = blockIdx.x;
        const float* M = ws + OFF_M + (long)bh * L_;
        int* Mtop = (int*)ws + OFF_MTOP + bh * NT_;

        float vals[16];
#pragma unroll
        for (int j = 0; j < 16; ++j) vals[j] = M[tid * 16 + j];
        float lv = NEG_BIG; int li = tid * 16;
#pragma unroll
        for (int j = 0; j < 16; ++j) {
            if (vals[j] > lv) { lv = vals[j]; li = tid * 16 + j; }
        }

        __shared__ float wbv[4];
        __shared__ int   wbi[4];
        int lane = tid & 63, w = tid >> 6;

        for (int r = 0; r < NT_; ++r) {
            float v = lv; int i = li;
#pragma unroll
            for (int off = 32; off; off >>= 1) {
                float v2 = __shfl_xor(v, off);
                int   i2 = __shfl_xor(i, off);
                if (v2 > v || (v2 == v && i2 < i)) { v = v2; i = i2; }
            }
            if (lane == 0) { wbv[w] = v; wbi[w] = i; }
            __syncthreads();
            float bv = wbv[0]; int bi = wbi[0];
#pragma unroll
            for (int g = 1; g < 4; ++g) {
                float v2 = wbv[g]; int i2 = wbi[g];
                if (v2 > bv || (v2 == bv && i2 < bi)) { bv = v2; bi = i2; }
            }
            if (tid == 0) Mtop[r] = bi;
            if ((bi >> 4) == tid) {
#pragma unroll
                for (int j = 0; j < 16; ++j)
                    if (j == (bi & 15)) vals[j] = NEG_BIG;
                lv = NEG_BIG; li = tid * 16;
#pragma unroll
                for (int j = 0; j < 16; ++j)
                    if (vals[j] > lv) { lv = vals[j]; li = tid * 16 + j; }
            }
            __syncthreads();
        }
    } else {
        // wave per (bh, ch): inclusive scan within chunk, offset from vsum
        int w = tid >> 6, d = tid & 63;
        int unit = (blockIdx.x - 16) * 4 + w;    // 0..511
        int bh = unit >> 5, ch = unit & 31;
        int b = bh >> 3, h = bh & 7;

        float acc = 0.f;
        for (int c = 0; c < ch; ++c)
            acc += ws[OFF_VSUM + (bh * NCHV + c) * 64 + d];

        const float* vp = V   + ((((long)b * L_ + (long)ch * CHV) * H_ + h) << 6) + d;
        float*       op = out + ((((long)b * L_ + (long)ch * CHV) * H_ + h) << 6) + d;
        for (int i = 0; i < CHV; ++i) {
            acc += vp[(long)i * (H_ * D_)];
            op[(long)i * (H_ * D_)] = acc;
        }
    }
}

// ---------------------------------------------------------------------------
// Kernel C: attention partials. Block = (bh, kc): 45 selected queries vs one
// 128-key chunk. K rows in registers, V chunk + P in LDS (56 KB).
// ---------------------------------------------------------------------------
__global__ __launch_bounds__(256) void kC(const float* __restrict__ Q,
                                          const float* __restrict__ Kt,
                                          const float* __restrict__ V,
                                          float* __restrict__ ws)
{
    __shared__ float Vlds[KC * 64];   // 32 KB
    __shared__ float P[NT_ * KC];     // 23 KB (scores -> exp weights)
    __shared__ int   qpos[NT_];

    int tid = threadIdx.x;
    int bh = blockIdx.x >> 5, kc = blockIdx.x & 31;
    int b = bh >> 3, h = bh & 7;
    int kbase = kc * KC;

    if (tid < NT_) qpos[tid] = ((const int*)ws)[OFF_MTOP + bh * NT_ + tid];

    // cooperative, coalesced V-chunk load (wave = one 256B row per step)
    {
        const float* vsrc = V + ((((long)b * L_ + kbase) * H_ + h) << 6);
#pragma unroll
        for (int i = 0; i < 32; ++i) {
            int e = i * 256 + tid;
            int r = e >> 6, d = e & 63;
            Vlds[e] = vsrc[(long)r * (H_ * D_) + d];
        }
    }
    __syncthreads();

    // QK: thread = (k, u-half); K row in 64 VGPRs, Q rows broadcast from L1
    int k = tid & 127, uh = tid >> 7;
    int kpos = kbase + k;
    {
        float4 krow[16];
        const float4* kp = (const float4*)(Kt + ((((long)b * L_ + kpos) * H_ + h) << 6));
#pragma unroll
        for (int j = 0; j < 16; ++j) krow[j] = kp[j];

        int u0 = uh ? 23 : 0, u1 = uh ? NT_ : 23;
        for (int u = u0; u < u1; ++u) {
            int qp_ = qpos[u];
            const float4* qrow = (const float4*)(Q + ((((long)b * L_ + qp_) * H_ + h) << 6));
            float acc = 0.f;
#pragma unroll
            for (int j = 0; j < 16; ++j) {
                float4 qv = qrow[j];
                acc += qv.x * krow[j].x + qv.y * krow[j].y +
                       qv.z * krow[j].z + qv.w * krow[j].w;
            }
            float sc = acc * SCALE;
            if (kpos > qp_) sc = NEG_BIG;   // causal mask
            P[u * KC + k] = sc;
        }
    }
    __syncthreads();

    // per-u softmax partials (wave w handles u = w, w+4, ...)
    int lane = tid & 63, w = tid >> 6;
    for (int u = w; u < NT_; u += 4) {
        float s0 = P[u * KC + lane];
        float s1 = P[u * KC + 64 + lane];
        float m = fmaxf(s0, s1);
#pragma unroll
        for (int off = 32; off; off >>= 1) m = fmaxf(m, __shfl_xor(m, off));
        float e0 = __expf(s0 - m), e1 = __expf(s1 - m);
        P[u * KC + lane]      = e0;
        P[u * KC + 64 + lane] = e1;
        float sm = e0 + e1;
#pragma unroll
        for (int off = 32; off; off >>= 1) sm += __shfl_xor(sm, off);
        if (lane == 0) {
            ws[OFF_MPART + (bh * NKC + kc) * NT_ + u] = m;
            ws[OFF_SPART + (bh * NKC + kc) * NT_ + u] = sm;
        }
    }
    __syncthreads();

    // PV: wave w accumulates ctx for u in {w, w+4, ...}; lane = d
    {
        float ctx[12];
#pragma unroll
        for (int j = 0; j < 12; ++j) ctx[j] = 0.f;
        for (int kk = 0; kk < KC; ++kk) {
            float v = Vlds[kk * 64 + lane];
#pragma unroll
            for (int j = 0; j < 12; ++j) {
                int u = w + j * 4;
                if (u < NT_) ctx[j] += P[u * KC + kk] * v;   // P broadcast read
            }
        }
#pragma unroll
        for (int j = 0; j < 12; ++j) {
            int u = w + j * 4;
            if (u < NT_)
                ws[OFF_CTXP + ((long)(bh * NKC + kc) * NT_ + u) * 64 + lane] = ctx[j];
        }
    }
}

// ---------------------------------------------------------------------------
// Kernel D: merge chunk partials (log-sum-exp) and overwrite selected rows
// ---------------------------------------------------------------------------
__global__ __launch_bounds__(256) void kD(float* __restrict__ out,
                                          const float* __restrict__ ws)
{
    int tid  = threadIdx.x;
    int w    = tid >> 6;
    int lane = tid & 63;
    int unit = blockIdx.x * 4 + w;       // 0..719
    if (unit >= BH_ * NT_) return;
    int bh = unit / NT_, u = unit - bh * NT_;
    int b = bh >> 3, h = bh & 7;

    float mc[NKC];
    float m = NEG_BIG;
#pragma unroll
    for (int c = 0; c < NKC; ++c) {
        mc[c] = ws[OFF_MPART + (bh * NKC + c) * NT_ + u];
        m = fmaxf(m, mc[c]);
    }
    float T = 0.f, ctx = 0.f;
#pragma unroll
    for (int c = 0; c < NKC; ++c) {
        float wgt = __expf(mc[c] - m);   // fully-masked chunks: exp(-1e30-m) = 0
        T   += ws[OFF_SPART + (bh * NKC + c) * NT_ + u] * wgt;
        ctx += ws[OFF_CTXP + ((long)(bh * NKC + c) * NT_ + u) * 64 + lane] * wgt;
    }
    int qp = ((const int*)ws)[OFF_MTOP + bh * NT_ + u];
    out[((((long)b * L_ + qp) * H_ + h) << 6) + lane] = ctx / T;
}

// ---------------------------------------------------------------------------
extern "C" void kernel_launch(void* const* d_in, const int* in_sizes, int n_in,
                              void* d_out, int out_size, void* d_ws, size_t ws_size,
                              hipStream_t stream)
{
    const float* Q    = (const float*)d_in[0];
    const float* K    = (const float*)d_in[1];
    const float* V    = (const float*)d_in[2];
    const int*   samp = (const int*)d_in[4];   // d_in[3] = attn_mask (unused)
    float* out = (float*)d_out;
    float* ws  = (float*)d_ws;

    // A: M scores (16384 blocks) + V chunk sums (128 blocks)
    kA<<<16512, 256, 0, stream>>>(Q, K, V, samp, ws);
    // B: top-45 (16 blocks) + cumsum write (128 blocks)
    kB<<<144, 256, 0, stream>>>(V, out, ws);
    // C: attention partials (16 bh x 32 key chunks)
    kC<<<512, 256, 0, stream>>>(Q, K, V, ws);
    // D: merge + scatter selected rows (720 waves)
    kD<<<180, 256, 0, stream>>>(out, ws);
}

// Round 2
// 251.278 us; speedup vs baseline: 1.3949x; 1.3949x over previous
//
#include <hip/hip_runtime.h>
#include <math.h>

// Problem constants (fixed by setup_inputs)
#define B_    2
#define L_    4096
#define H_    8
#define D_    64
#define S_    45      // sample_k
#define NT_   45      // n_top
#define BH_   16      // B*H
#define CHV   64      // cumsum chunk length
#define NCHV  64      // L_/CHV
#define KC    128     // attention key-chunk length
#define NKC   32      // L_/KC
#define SCALE 0.125f  // 1/sqrt(64)
#define NEG_BIG (-1e30f)

// Workspace layout (float element offsets; ints share the same 4B slots).
// VSUM is only live between kA and kB-part2; CTXP is written in kC, so
// VSUM overlays the start of the CTXP region.
#define OFF_M     0         // 65536 floats: M[bh][q]
#define OFF_MTOP  65536     // 720 ints:    M_top[bh][u]
#define OFF_MPART 66304     // 23040 floats: m partial [bh][kc][u]
#define OFF_SPART 89344     // 23040 floats: sumexp partial
#define OFF_CTXP  112384    // 1474560 floats: ctx partial [bh][kc][u][d]
#define OFF_VSUM  112384    // 65536 floats: vsum[bh][ch][d] (overlays CTXP)

// ---------------------------------------------------------------------------
// Kernel A: part 1 (blocks < 8192): M[b,h,q] for all 8 h of one (b,q).
//   Wave layout: w = (head-half hh, sample-half sh). Per sample one wave
//   issues ONE coalesced 1KB load covering 4 heads (lane = 16B chunk),
//   dot4 per lane, 4-step shfl_xor reduction within 16-lane head groups.
//           part 2 (blocks >= 8192): per-chunk V sums for the cumsum
// ---------------------------------------------------------------------------
__global__ __launch_bounds__(256) void kA(const float* __restrict__ Q,
                                          const float* __restrict__ Kt,
                                          const float* __restrict__ V,
                                          const int* __restrict__ samp,
                                          float* __restrict__ ws)
{
    int tid  = threadIdx.x;
    int w    = tid >> 6;
    int lane = tid & 63;

    if (blockIdx.x < 8192) {
        int b = blockIdx.x >> 12, q = blockIdx.x & 4095;

        __shared__ int   sidx[S_];
        __shared__ float redm[8][2], reds[8][2];

        if (tid < S_) sidx[tid] = samp[q * S_ + tid];
        __syncthreads();

        int hh = w >> 1;              // head-half: heads hh*4 .. hh*4+3
        int sh = w & 1;               // sample-half
        int h4 = lane >> 4;           // head within half
        int h  = hh * 4 + h4;
        int d0 = (lane & 15) * 4;

        const float4 q4 = *(const float4*)(Q + ((((long)b * L_ + q) * H_ + h) << 6) + d0);

        float mx = NEG_BIG, sm = 0.f;
        int s0 = sh ? 23 : 0, s1 = sh ? S_ : 23;
        for (int s = s0; s < s1; ++s) {
            int idx = sidx[s];
            // contiguous 1KB: 4 head-slices of row idx; lane reads 16B chunk
            const float4 k4 = *(const float4*)(Kt +
                ((((long)b * L_ + idx) * H_ + hh * 4) << 6) + lane * 4);
            float p = q4.x * k4.x + q4.y * k4.y + q4.z * k4.z + q4.w * k4.w;
            p += __shfl_xor(p, 1);
            p += __shfl_xor(p, 2);
            p += __shfl_xor(p, 4);
            p += __shfl_xor(p, 8);    // p = full 64-dot, uniform in 16-lane group
            mx = fmaxf(mx, p);
            sm += p;
        }
        if ((lane & 15) == 0) { redm[h][sh] = mx; reds[h][sh] = sm; }
        __syncthreads();
        if (tid < 8) {
            float m = fmaxf(redm[tid][0], redm[tid][1]);
            float s = reds[tid][0] + reds[tid][1];
            ws[OFF_M + (b * 8 + tid) * L_ + q] = m - s * (1.0f / (float)L_);
        }
    } else {
        // wave per (bh, ch): vsum[bh][ch][d] = sum_{i<CHV} V[b, ch*CHV+i, h, d]
        int unit = (blockIdx.x - 8192) * 4 + w;   // 0..1023
        int bh = unit >> 6, ch = unit & 63;
        int b = bh >> 3, h = bh & 7;
        int d = lane;
        const float* vp = V + ((((long)b * L_ + (long)ch * CHV) * H_ + h) << 6) + d;
        float ssum = 0.f;
        for (int i = 0; i < CHV; ++i) ssum += vp[(long)i * (H_ * D_)];
        ws[OFF_VSUM + unit * 64 + d] = ssum;
    }
}

// ---------------------------------------------------------------------------
// Kernel B: part 1 (blocks < 16): top-45 of M per (b,h) (iterative argmax,
//           lowest-index tie-break to match jax.lax.top_k)
//           part 2 (blocks >= 16): cumsum write: out = prefix-sum of V
// ---------------------------------------------------------------------------
__global__ __launch_bounds__(256) void kB(const float* __restrict__ V,
                                          float* __restrict__ out,
                                          float* __restrict__ ws)
{
    int tid = threadIdx.x;

    if (blockIdx.x < 16) {
        int bh = blockIdx.x;
        const float* M = ws + OFF_M + (long)bh * L_;
        int* Mtop = (int*)ws + OFF_MTOP + bh * NT_;

        float vals[16];
#pragma unroll
        for (int j = 0; j < 16; ++j) vals[j] = M[tid * 16 + j];
        float lv = NEG_BIG; int li = tid * 16;
#pragma unroll
        for (int j = 0; j < 16; ++j) {
            if (vals[j] > lv) { lv = vals[j]; li = tid * 16 + j; }
        }

        __shared__ float wbv[4];
        __shared__ int   wbi[4];
        int lane = tid & 63, w = tid >> 6;

        for (int r = 0; r < NT_; ++r) {
            float v = lv; int i = li;
#pragma unroll
            for (int off = 32; off; off >>= 1) {
                float v2 = __shfl_xor(v, off);
                int   i2 = __shfl_xor(i, off);
                if (v2 > v || (v2 == v && i2 < i)) { v = v2; i = i2; }
            }
            if (lane == 0) { wbv[w] = v; wbi[w] = i; }
            __syncthreads();
            float bv = wbv[0]; int bi = wbi[0];
#pragma unroll
            for (int g = 1; g < 4; ++g) {
                float v2 = wbv[g]; int i2 = wbi[g];
                if (v2 > bv || (v2 == bv && i2 < bi)) { bv = v2; bi = i2; }
            }
            if (tid == 0) Mtop[r] = bi;
            if ((bi >> 4) == tid) {
#pragma unroll
                for (int j = 0; j < 16; ++j)
                    if (j == (bi & 15)) vals[j] = NEG_BIG;
                lv = NEG_BIG; li = tid * 16;
#pragma unroll
                for (int j = 0; j < 16; ++j)
                    if (vals[j] > lv) { lv = vals[j]; li = tid * 16 + j; }
            }
            __syncthreads();
        }
    } else {
        // wave per (bh, ch): inclusive scan within chunk, offset from vsum
        int w = tid >> 6, d = tid & 63;
        int unit = (blockIdx.x - 16) * 4 + w;    // 0..1023
        int bh = unit >> 6, ch = unit & 63;
        int b = bh >> 3, h = bh & 7;

        float acc = 0.f;
        for (int c = 0; c < ch; ++c)
            acc += ws[OFF_VSUM + (bh * NCHV + c) * 64 + d];

        const float* vp = V   + ((((long)b * L_ + (long)ch * CHV) * H_ + h) << 6) + d;
        float*       op = out + ((((long)b * L_ + (long)ch * CHV) * H_ + h) << 6) + d;
        for (int i = 0; i < CHV; ++i) {
            acc += vp[(long)i * (H_ * D_)];
            op[(long)i * (H_ * D_)] = acc;
        }
    }
}

// ---------------------------------------------------------------------------
// Kernel C: attention partials. Block = (bh, kc): 45 selected queries vs one
// 128-key chunk. K rows in registers, V chunk + P in LDS (56 KB).
// ---------------------------------------------------------------------------
__global__ __launch_bounds__(256) void kC(const float* __restrict__ Q,
                                          const float* __restrict__ Kt,
                                          const float* __restrict__ V,
                                          float* __restrict__ ws)
{
    __shared__ float Vlds[KC * 64];   // 32 KB
    __shared__ float P[NT_ * KC];     // 23 KB (scores -> exp weights)
    __shared__ int   qpos[NT_];

    int tid = threadIdx.x;
    int bh = blockIdx.x >> 5, kc = blockIdx.x & 31;
    int b = bh >> 3, h = bh & 7;
    int kbase = kc * KC;

    if (tid < NT_) qpos[tid] = ((const int*)ws)[OFF_MTOP + bh * NT_ + tid];

    // cooperative V-chunk load (each instr: 4 rows x 64B contiguous segments)
    {
        const float* vsrc = V + ((((long)b * L_ + kbase) * H_ + h) << 6);
#pragma unroll
        for (int i = 0; i < 32; ++i) {
            int e = i * 256 + tid;
            int r = e >> 6, d = e & 63;
            Vlds[e] = vsrc[(long)r * (H_ * D_) + d];
        }
    }
    __syncthreads();

    // QK: thread = (k, u-half); K row in 64 VGPRs, Q rows broadcast from L1
    int k = tid & 127, uh = tid >> 7;
    int kpos = kbase + k;
    {
        float4 krow[16];
        const float4* kp = (const float4*)(Kt + ((((long)b * L_ + kpos) * H_ + h) << 6));
#pragma unroll
        for (int j = 0; j < 16; ++j) krow[j] = kp[j];

        int u0 = uh ? 23 : 0, u1 = uh ? NT_ : 23;
        for (int u = u0; u < u1; ++u) {
            int qp_ = qpos[u];
            const float4* qrow = (const float4*)(Q + ((((long)b * L_ + qp_) * H_ + h) << 6));
            float acc = 0.f;
#pragma unroll
            for (int j = 0; j < 16; ++j) {
                float4 qv = qrow[j];
                acc += qv.x * krow[j].x + qv.y * krow[j].y +
                       qv.z * krow[j].z + qv.w * krow[j].w;
            }
            float sc = acc * SCALE;
            if (kpos > qp_) sc = NEG_BIG;   // causal mask
            P[u * KC + k] = sc;
        }
    }
    __syncthreads();

    // per-u softmax partials (wave w handles u = w, w+4, ...)
    int lane = tid & 63, w = tid >> 6;
    for (int u = w; u < NT_; u += 4) {
        float s0 = P[u * KC + lane];
        float s1 = P[u * KC + 64 + lane];
        float m = fmaxf(s0, s1);
#pragma unroll
        for (int off = 32; off; off >>= 1) m = fmaxf(m, __shfl_xor(m, off));
        float e0 = __expf(s0 - m), e1 = __expf(s1 - m);
        P[u * KC + lane]      = e0;
        P[u * KC + 64 + lane] = e1;
        float sm = e0 + e1;
#pragma unroll
        for (int off = 32; off; off >>= 1) sm += __shfl_xor(sm, off);
        if (lane == 0) {
            ws[OFF_MPART + (bh * NKC + kc) * NT_ + u] = m;
            ws[OFF_SPART + (bh * NKC + kc) * NT_ + u] = sm;
        }
    }
    __syncthreads();

    // PV: wave w accumulates ctx for u in {w, w+4, ...}; lane = d.
    // P read as broadcast float4 (4 kk at once) -> 4x fewer LDS instrs.
    {
        float ctx[12];
#pragma unroll
        for (int j = 0; j < 12; ++j) ctx[j] = 0.f;
        for (int kk = 0; kk < KC; kk += 4) {
            float v0 = Vlds[(kk + 0) * 64 + lane];
            float v1 = Vlds[(kk + 1) * 64 + lane];
            float v2 = Vlds[(kk + 2) * 64 + lane];
            float v3 = Vlds[(kk + 3) * 64 + lane];
#pragma unroll
            for (int j = 0; j < 12; ++j) {
                int u = w + j * 4;
                if (u < NT_) {
                    float4 pv = *(const float4*)&P[u * KC + kk];  // broadcast
                    ctx[j] += pv.x * v0 + pv.y * v1 + pv.z * v2 + pv.w * v3;
                }
            }
        }
#pragma unroll
        for (int j = 0; j < 12; ++j) {
            int u = w + j * 4;
            if (u < NT_)
                ws[OFF_CTXP + ((long)(bh * NKC + kc) * NT_ + u) * 64 + lane] = ctx[j];
        }
    }
}

// ---------------------------------------------------------------------------
// Kernel D: merge chunk partials (log-sum-exp) and overwrite selected rows
// ---------------------------------------------------------------------------
__global__ __launch_bounds__(256) void kD(float* __restrict__ out,
                                          const float* __restrict__ ws)
{
    int tid  = threadIdx.x;
    int w    = tid >> 6;
    int lane = tid & 63;
    int unit = blockIdx.x * 4 + w;       // 0..719
    if (unit >= BH_ * NT_) return;
    int bh = unit / NT_, u = unit - bh * NT_;
    int b = bh >> 3, h = bh & 7;

    float mc[NKC];
    float m = NEG_BIG;
#pragma unroll
    for (int c = 0; c < NKC; ++c) {
        mc[c] = ws[OFF_MPART + (bh * NKC + c) * NT_ + u];
        m = fmaxf(m, mc[c]);
    }
    float T = 0.f, ctx = 0.f;
#pragma unroll
    for (int c = 0; c < NKC; ++c) {
        float wgt = __expf(mc[c] - m);   // fully-masked chunks: exp(-1e30-m) = 0
        T   += ws[OFF_SPART + (bh * NKC + c) * NT_ + u] * wgt;
        ctx += ws[OFF_CTXP + ((long)(bh * NKC + c) * NT_ + u) * 64 + lane] * wgt;
    }
    int qp = ((const int*)ws)[OFF_MTOP + bh * NT_ + u];
    out[((((long)b * L_ + qp) * H_ + h) << 6) + lane] = ctx / T;
}

// ---------------------------------------------------------------------------
extern "C" void kernel_launch(void* const* d_in, const int* in_sizes, int n_in,
                              void* d_out, int out_size, void* d_ws, size_t ws_size,
                              hipStream_t stream)
{
    const float* Q    = (const float*)d_in[0];
    const float* K    = (const float*)d_in[1];
    const float* V    = (const float*)d_in[2];
    const int*   samp = (const int*)d_in[4];   // d_in[3] = attn_mask (unused)
    float* out = (float*)d_out;
    float* ws  = (float*)d_ws;

    // A: M scores (8192 blocks, one per (b,q)) + V chunk sums (256 blocks)
    kA<<<8448, 256, 0, stream>>>(Q, K, V, samp, ws);
    // B: top-45 (16 blocks) + cumsum write (256 blocks)
    kB<<<272, 256, 0, stream>>>(V, out, ws);
    // C: attention partials (16 bh x 32 key chunks)
    kC<<<512, 256, 0, stream>>>(Q, K, V, ws);
    // D: merge + scatter selected rows (720 waves)
    kD<<<180, 256, 0, stream>>>(out, ws);
}

// Round 3
// 250.436 us; speedup vs baseline: 1.3995x; 1.0034x over previous
//
#include <hip/hip_runtime.h>
#include <math.h>

// Problem constants (fixed by setup_inputs)
#define B_    2
#define L_    4096
#define H_    8
#define D_    64
#define S_    45      // sample_k
#define NT_   45      // n_top
#define BH_   16      // B*H
#define CHV   64      // cumsum chunk length
#define NCHV  64      // L_/CHV
#define KC    128     // attention key-chunk length
#define NKC   32      // L_/KC
#define SCALE 0.125f  // 1/sqrt(64)
#define NEG_BIG (-1e30f)

// Workspace layout (float element offsets; ints share the same 4B slots).
// VSUM is only live between kA and kB-part2; CTXP is written in kC, so
// VSUM overlays the start of the CTXP region.
#define OFF_M     0         // 65536 floats: M[bh][q]
#define OFF_MTOP  65536     // 720 ints:    M_top[bh][u]
#define OFF_MPART 66304     // 23040 floats: m partial [bh][kc][u]
#define OFF_SPART 89344     // 23040 floats: sumexp partial
#define OFF_CTXP  112384    // 1474560 floats: ctx partial [bh][kc][u][d]
#define OFF_VSUM  112384    // 65536 floats: vsum[bh][ch][d] (overlays CTXP)

// ---------------------------------------------------------------------------
// Kernel A: part 1 (blocks < 8192): M[b,h,q] for all 8 h of one (b,q).
//   Wave = (head-half hh, sample-half sh). Per sample one coalesced 1KB load
//   covers 4 heads (lane = 16B chunk); dot4 + 4-step shfl_xor reduce in
//   16-lane head groups. Samples batched 8-deep so 8 gathers are in flight.
//           part 2 (blocks >= 8192): per-chunk V sums, 16 loads in flight.
// ---------------------------------------------------------------------------
__global__ __launch_bounds__(256) void kA(const float* __restrict__ Q,
                                          const float* __restrict__ Kt,
                                          const float* __restrict__ V,
                                          const int* __restrict__ samp,
                                          float* __restrict__ ws)
{
    int tid  = threadIdx.x;
    int w    = tid >> 6;
    int lane = tid & 63;

    if (blockIdx.x < 8192) {
        int b = blockIdx.x >> 12, q = blockIdx.x & 4095;

        __shared__ int   sidx[S_];
        __shared__ float redm[8][2], reds[8][2];

        if (tid < S_) sidx[tid] = samp[q * S_ + tid];
        __syncthreads();

        int hh = w >> 1;              // head-half: heads hh*4 .. hh*4+3
        int sh = w & 1;               // sample-half
        int h4 = lane >> 4;           // head within half
        int h  = hh * 4 + h4;

        const float4 q4 = *(const float4*)(Q +
            ((((long)b * L_ + q) * H_ + hh * 4) << 6) + lane * 4);

        const float* kb_base = Kt + (((long)b * L_ * H_ + hh * 4) << 6) + lane * 4;

        // sh=0 covers s=0..22, sh=1 covers s=22..44 (s=22 dup: max-safe,
        // masked out of the sum). 24 trips (last clamped) -> fully unrollable.
        float mx = NEG_BIG, sm = 0.f;
#pragma unroll
        for (int jb = 0; jb < 24; jb += 8) {
            float4 kb[8];
#pragma unroll
            for (int j = 0; j < 8; ++j) {
                int jj = jb + j;
                int jc = jj < 23 ? jj : 22;            // clamp 24th trip
                int s  = sh * 22 + jc;
                kb[j] = *(const float4*)(kb_base + (((long)sidx[s] * H_) << 6));
            }
#pragma unroll
            for (int j = 0; j < 8; ++j) {
                int jj = jb + j;
                float p = q4.x * kb[j].x + q4.y * kb[j].y +
                          q4.z * kb[j].z + q4.w * kb[j].w;
                p += __shfl_xor(p, 1);
                p += __shfl_xor(p, 2);
                p += __shfl_xor(p, 4);
                p += __shfl_xor(p, 8);   // full 64-dot, uniform per 16-lane group
                mx = fmaxf(mx, p);       // duplicates harmless for max
                bool valid = (jj < 23) && !(sh == 1 && jj == 0);
                sm += valid ? p : 0.f;
            }
        }
        if ((lane & 15) == 0) { redm[h][sh] = mx; reds[h][sh] = sm; }
        __syncthreads();
        if (tid < 8) {
            float m = fmaxf(redm[tid][0], redm[tid][1]);
            float s = reds[tid][0] + reds[tid][1];
            ws[OFF_M + (b * 8 + tid) * L_ + q] = m - s * (1.0f / (float)L_);
        }
    } else {
        // wave per (bh, ch): vsum[bh][ch][d] = sum_{i<CHV} V[b, ch*CHV+i, h, d]
        int unit = (blockIdx.x - 8192) * 4 + w;   // 0..1023
        int bh = unit >> 6, ch = unit & 63;
        int b = bh >> 3, h = bh & 7;
        int d = lane;
        const float* vp = V + ((((long)b * L_ + (long)ch * CHV) * H_ + h) << 6) + d;
        float ssum = 0.f;
#pragma unroll
        for (int ib = 0; ib < CHV; ib += 16) {
            float vb[16];
#pragma unroll
            for (int j = 0; j < 16; ++j) vb[j] = vp[(long)(ib + j) * (H_ * D_)];
#pragma unroll
            for (int j = 0; j < 16; ++j) ssum += vb[j];
        }
        ws[OFF_VSUM + unit * 64 + d] = ssum;
    }
}

// ---------------------------------------------------------------------------
// Kernel B: part 1 (blocks < 16): top-45 of M per (b,h) (iterative argmax,
//           lowest-index tie-break to match jax.lax.top_k)
//           part 2 (blocks >= 16): cumsum write, 16 loads in flight
// ---------------------------------------------------------------------------
__global__ __launch_bounds__(256) void kB(const float* __restrict__ V,
                                          float* __restrict__ out,
                                          float* __restrict__ ws)
{
    int tid = threadIdx.x;

    if (blockIdx.x < 16) {
        int bh = blockIdx.x;
        const float* M = ws + OFF_M + (long)bh * L_;
        int* Mtop = (int*)ws + OFF_MTOP + bh * NT_;

        float vals[16];
#pragma unroll
        for (int j = 0; j < 16; ++j) vals[j] = M[tid * 16 + j];
        float lv = NEG_BIG; int li = tid * 16;
#pragma unroll
        for (int j = 0; j < 16; ++j) {
            if (vals[j] > lv) { lv = vals[j]; li = tid * 16 + j; }
        }

        __shared__ float wbv[4];
        __shared__ int   wbi[4];
        int lane = tid & 63, w = tid >> 6;

        for (int r = 0; r < NT_; ++r) {
            float v = lv; int i = li;
#pragma unroll
            for (int off = 32; off; off >>= 1) {
                float v2 = __shfl_xor(v, off);
                int   i2 = __shfl_xor(i, off);
                if (v2 > v || (v2 == v && i2 < i)) { v = v2; i = i2; }
            }
            if (lane == 0) { wbv[w] = v; wbi[w] = i; }
            __syncthreads();
            float bv = wbv[0]; int bi = wbi[0];
#pragma unroll
            for (int g = 1; g < 4; ++g) {
                float v2 = wbv[g]; int i2 = wbi[g];
                if (v2 > bv || (v2 == bv && i2 < bi)) { bv = v2; bi = i2; }
            }
            if (tid == 0) Mtop[r] = bi;
            if ((bi >> 4) == tid) {
#pragma unroll
                for (int j = 0; j < 16; ++j)
                    if (j == (bi & 15)) vals[j] = NEG_BIG;
                lv = NEG_BIG; li = tid * 16;
#pragma unroll
                for (int j = 0; j < 16; ++j)
                    if (vals[j] > lv) { lv = vals[j]; li = tid * 16 + j; }
            }
            __syncthreads();
        }
    } else {
        // wave per (bh, ch): inclusive scan within chunk, offset from vsum
        int w = tid >> 6, d = tid & 63;
        int unit = (blockIdx.x - 16) * 4 + w;    // 0..1023
        int bh = unit >> 6, ch = unit & 63;
        int b = bh >> 3, h = bh & 7;

        // prefix over earlier chunk sums, 8 loads in flight
        float acc = 0.f;
        {
            const float* vs = ws + OFF_VSUM + (long)bh * NCHV * 64 + d;
            int c = 0;
            for (; c + 8 <= ch; c += 8) {
                float vb[8];
#pragma unroll
                for (int j = 0; j < 8; ++j) vb[j] = vs[(c + j) * 64];
#pragma unroll
                for (int j = 0; j < 8; ++j) acc += vb[j];
            }
            for (; c < ch; ++c) acc += vs[c * 64];
        }

        const float* vp = V   + ((((long)b * L_ + (long)ch * CHV) * H_ + h) << 6) + d;
        float*       op = out + ((((long)b * L_ + (long)ch * CHV) * H_ + h) << 6) + d;
#pragma unroll
        for (int ib = 0; ib < CHV; ib += 16) {
            float vb[16];
#pragma unroll
            for (int j = 0; j < 16; ++j) vb[j] = vp[(long)(ib + j) * (H_ * D_)];
#pragma unroll
            for (int j = 0; j < 16; ++j) {
                acc += vb[j];
                op[(long)(ib + j) * (H_ * D_)] = acc;
            }
        }
    }
}

// ---------------------------------------------------------------------------
// Kernel C: attention partials. Block = (bh, kc): 45 selected queries vs one
// 128-key chunk. K rows in registers, V chunk + P in LDS (56 KB).
// ---------------------------------------------------------------------------
__global__ __launch_bounds__(256) void kC(const float* __restrict__ Q,
                                          const float* __restrict__ Kt,
                                          const float* __restrict__ V,
                                          float* __restrict__ ws)
{
    __shared__ float Vlds[KC * 64];   // 32 KB
    __shared__ float P[NT_ * KC];     // 23 KB (scores -> exp weights)
    __shared__ int   qpos[NT_];

    int tid = threadIdx.x;
    int bh = blockIdx.x >> 5, kc = blockIdx.x & 31;
    int b = bh >> 3, h = bh & 7;
    int kbase = kc * KC;

    if (tid < NT_) qpos[tid] = ((const int*)ws)[OFF_MTOP + bh * NT_ + tid];

    // cooperative V-chunk load (each instr: 4 rows x 64B contiguous segments)
    {
        const float* vsrc = V + ((((long)b * L_ + kbase) * H_ + h) << 6);
#pragma unroll
        for (int i = 0; i < 32; ++i) {
            int e = i * 256 + tid;
            int r = e >> 6, d = e & 63;
            Vlds[e] = vsrc[(long)r * (H_ * D_) + d];
        }
    }
    __syncthreads();

    // QK: thread = (k, u-half); K row in 64 VGPRs, Q rows broadcast from L1.
    // Fixed 23-trip per half (u=22 computed by both halves; same value, benign
    // double-write) so the loop can unroll/pipeline.
    int k = tid & 127, uh = tid >> 7;
    int kpos = kbase + k;
    {
        float4 krow[16];
        const float4* kp = (const float4*)(Kt + ((((long)b * L_ + kpos) * H_ + h) << 6));
#pragma unroll
        for (int j = 0; j < 16; ++j) krow[j] = kp[j];

#pragma unroll 2
        for (int j = 0; j < 23; ++j) {
            int u = uh * 22 + j;
            int qp_ = qpos[u];
            const float4* qrow = (const float4*)(Q + ((((long)b * L_ + qp_) * H_ + h) << 6));
            float acc = 0.f;
#pragma unroll
            for (int jj = 0; jj < 16; ++jj) {
                float4 qv = qrow[jj];
                acc += qv.x * krow[jj].x + qv.y * krow[jj].y +
                       qv.z * krow[jj].z + qv.w * krow[jj].w;
            }
            float sc = acc * SCALE;
            if (kpos > qp_) sc = NEG_BIG;   // causal mask
            P[u * KC + k] = sc;
        }
    }
    __syncthreads();

    // per-u softmax partials (wave w handles u = w, w+4, ...)
    int lane = tid & 63, w = tid >> 6;
    for (int u = w; u < NT_; u += 4) {
        float s0 = P[u * KC + lane];
        float s1 = P[u * KC + 64 + lane];
        float m = fmaxf(s0, s1);
#pragma unroll
        for (int off = 32; off; off >>= 1) m = fmaxf(m, __shfl_xor(m, off));
        float e0 = __expf(s0 - m), e1 = __expf(s1 - m);
        P[u * KC + lane]      = e0;
        P[u * KC + 64 + lane] = e1;
        float sm = e0 + e1;
#pragma unroll
        for (int off = 32; off; off >>= 1) sm += __shfl_xor(sm, off);
        if (lane == 0) {
            ws[OFF_MPART + (bh * NKC + kc) * NT_ + u] = m;
            ws[OFF_SPART + (bh * NKC + kc) * NT_ + u] = sm;
        }
    }
    __syncthreads();

    // PV: wave w accumulates ctx for u in {w, w+4, ...}; lane = d.
    // P read as broadcast float4 (4 kk at once) -> 4x fewer LDS instrs.
    {
        float ctx[12];
#pragma unroll
        for (int j = 0; j < 12; ++j) ctx[j] = 0.f;
        for (int kk = 0; kk < KC; kk += 4) {
            float v0 = Vlds[(kk + 0) * 64 + lane];
            float v1 = Vlds[(kk + 1) * 64 + lane];
            float v2 = Vlds[(kk + 2) * 64 + lane];
            float v3 = Vlds[(kk + 3) * 64 + lane];
#pragma unroll
            for (int j = 0; j < 12; ++j) {
                int u = w + j * 4;
                if (u < NT_) {
                    float4 pv = *(const float4*)&P[u * KC + kk];  // broadcast
                    ctx[j] += pv.x * v0 + pv.y * v1 + pv.z * v2 + pv.w * v3;
                }
            }
        }
#pragma unroll
        for (int j = 0; j < 12; ++j) {
            int u = w + j * 4;
            if (u < NT_)
                ws[OFF_CTXP + ((long)(bh * NKC + kc) * NT_ + u) * 64 + lane] = ctx[j];
        }
    }
}

// ---------------------------------------------------------------------------
// Kernel D: merge chunk partials (log-sum-exp) and overwrite selected rows
// ---------------------------------------------------------------------------
__global__ __launch_bounds__(256) void kD(float* __restrict__ out,
                                          const float* __restrict__ ws)
{
    int tid  = threadIdx.x;
    int w    = tid >> 6;
    int lane = tid & 63;
    int unit = blockIdx.x * 4 + w;       // 0..719
    if (unit >= BH_ * NT_) return;
    int bh = unit / NT_, u = unit - bh * NT_;
    int b = bh >> 3, h = bh & 7;

    float mc[NKC];
    float m = NEG_BIG;
#pragma unroll
    for (int c = 0; c < NKC; ++c) {
        mc[c] = ws[OFF_MPART + (bh * NKC + c) * NT_ + u];
        m = fmaxf(m, mc[c]);
    }
    float T = 0.f, ctx = 0.f;
#pragma unroll
    for (int c = 0; c < NKC; ++c) {
        float wgt = __expf(mc[c] - m);   // fully-masked chunks: exp(-1e30-m) = 0
        T   += ws[OFF_SPART + (bh * NKC + c) * NT_ + u] * wgt;
        ctx += ws[OFF_CTXP + ((long)(bh * NKC + c) * NT_ + u) * 64 + lane] * wgt;
    }
    int qp = ((const int*)ws)[OFF_MTOP + bh * NT_ + u];
    out[((((long)b * L_ + qp) * H_ + h) << 6) + lane] = ctx / T;
}

// ---------------------------------------------------------------------------
extern "C" void kernel_launch(void* const* d_in, const int* in_sizes, int n_in,
                              void* d_out, int out_size, void* d_ws, size_t ws_size,
                              hipStream_t stream)
{
    const float* Q    = (const float*)d_in[0];
    const float* K    = (const float*)d_in[1];
    const float* V    = (const float*)d_in[2];
    const int*   samp = (const int*)d_in[4];   // d_in[3] = attn_mask (unused)
    float* out = (float*)d_out;
    float* ws  = (float*)d_ws;

    // A: M scores (8192 blocks, one per (b,q)) + V chunk sums (256 blocks)
    kA<<<8448, 256, 0, stream>>>(Q, K, V, samp, ws);
    // B: top-45 (16 blocks) + cumsum write (256 blocks)
    kB<<<272, 256, 0, stream>>>(V, out, ws);
    // C: attention partials (16 bh x 32 key chunks)
    kC<<<512, 256, 0, stream>>>(Q, K, V, ws);
    // D: merge + scatter selected rows (720 waves)
    kD<<<180, 256, 0, stream>>>(out, ws);
}

// Round 4
// 226.334 us; speedup vs baseline: 1.5486x; 1.1065x over previous
//
#include <hip/hip_runtime.h>
#include <math.h>

// Problem constants (fixed by setup_inputs)
#define B_    2
#define L_    4096
#define H_    8
#define D_    64
#define S_    45      // sample_k
#define NT_   45      // n_top
#define BH_   16      // B*H
#define CHV   64      // cumsum chunk length
#define NCHV  64      // L_/CHV
#define KC    128     // attention key-chunk length
#define NKC   32      // L_/KC
#define SCALE 0.125f  // 1/sqrt(64)
#define NEG_BIG (-1e30f)

// Workspace layout (float element offsets; ints share the same 4B slots).
// VSUM is only live between kA and kB-part2; CTXP is written in kC, so
// VSUM overlays the start of the CTXP region.
#define OFF_M     0         // 65536 floats: M[bh][q]
#define OFF_MTOP  65536     // 720 ints:    M_top[bh][u]
#define OFF_MPART 66304     // 23040 floats: m partial [bh][u][kc]
#define OFF_SPART 89344     // 23040 floats: sumexp partial [bh][u][kc]
#define OFF_CTXP  112384    // 1474560 floats: ctx partial [bh][kc][u][d]
#define OFF_VSUM  112384    // 65536 floats: vsum[bh][ch][d] (overlays CTXP)

// DPP row-rotate add: rotations by 1,2,4,8 within a 16-lane row sum the row.
// VALU-pipe (no ds_swizzle), full-rate.
template <int CTRL>
__device__ __forceinline__ float dpp_ror_f(float x) {
    int y = __builtin_amdgcn_update_dpp(0, __float_as_int(x), CTRL, 0xF, 0xF, false);
    return __int_as_float(y);
}

// ---------------------------------------------------------------------------
// Kernel A: part 1 (blocks < 16384): block = (b, q, hh) with 128 threads.
//   XCD-slab swizzle: blockIdx%8 = XCD (round-robin dispatch); slab
//   (b,hh) = 4096 rows x 1KB = 4MB = one XCD's L2. Each XCD pair owns one
//   slab -> gathers become L2 hits.
//   Per sample one coalesced 1KB load covers 4 heads (lane = 16B chunk);
//   dot4 + 4-step DPP row-rotate reduce in 16-lane head groups.
//           part 2 (blocks >= 16384): per-chunk V sums, 16 loads in flight.
// ---------------------------------------------------------------------------
__global__ __launch_bounds__(128) void kA(const float* __restrict__ Q,
                                          const float* __restrict__ Kt,
                                          const float* __restrict__ V,
                                          const int* __restrict__ samp,
                                          float* __restrict__ ws)
{
    int tid  = threadIdx.x;
    int w    = tid >> 6;          // 0..1
    int lane = tid & 63;

    if (blockIdx.x < 16384) {
        // i%8 = XCD; slab = xcd>>1 in [0,4): b = slab>>1, hh = slab&1
        int i   = blockIdx.x;
        int xcd = i & 7;
        int b   = xcd >> 2;
        int hh  = (xcd >> 1) & 1;
        int q   = ((i >> 3) << 1) | (xcd & 1);   // 2048 j-slots x 2 = 4096 q

        __shared__ int   sidx[S_];
        __shared__ float redm[4][2], reds[4][2];

        if (tid < S_) sidx[tid] = samp[q * S_ + tid];
        __syncthreads();

        int sh = w;                   // sample-half
        int h4 = lane >> 4;           // head within half
        int h  = hh * 4 + h4;

        const float4 q4 = *(const float4*)(Q +
            ((((long)b * L_ + q) * H_ + hh * 4) << 6) + lane * 4);

        const float* kb_base = Kt + (((long)b * L_ * H_ + hh * 4) << 6) + lane * 4;

        // sh=0 covers s=0..22, sh=1 covers s=22..44 (s=22 dup: max-safe,
        // masked out of the sum). 24 trips (last clamped), 12-deep batches.
        float mx = NEG_BIG, sm = 0.f;
#pragma unroll
        for (int jb = 0; jb < 24; jb += 12) {
            float4 kb[12];
#pragma unroll
            for (int j = 0; j < 12; ++j) {
                int jj = jb + j;
                int jc = jj < 23 ? jj : 22;            // clamp 24th trip
                int s  = sh * 22 + jc;
                kb[j] = *(const float4*)(kb_base + (((long)sidx[s] * H_) << 6));
            }
#pragma unroll
            for (int j = 0; j < 12; ++j) {
                int jj = jb + j;
                float p = q4.x * kb[j].x + q4.y * kb[j].y +
                          q4.z * kb[j].z + q4.w * kb[j].w;
                p += dpp_ror_f<0x121>(p);   // ror 1
                p += dpp_ror_f<0x122>(p);   // ror 2
                p += dpp_ror_f<0x124>(p);   // ror 4
                p += dpp_ror_f<0x128>(p);   // ror 8 -> row sum (16 lanes)
                mx = fmaxf(mx, p);          // duplicates harmless for max
                bool valid = (jj < 23) && !(sh == 1 && jj == 0);
                sm += valid ? p : 0.f;
            }
        }
        if ((lane & 15) == 0) { redm[h4][sh] = mx; reds[h4][sh] = sm; }
        __syncthreads();
        if (tid < 4) {
            float m = fmaxf(redm[tid][0], redm[tid][1]);
            float s = reds[tid][0] + reds[tid][1];
            ws[OFF_M + ((long)(b * 8 + hh * 4 + tid)) * L_ + q] = m - s * (1.0f / (float)L_);
        }
    } else {
        // wave per (bh, ch): vsum[bh][ch][d] = sum_{i<CHV} V[b, ch*CHV+i, h, d]
        int unit = (blockIdx.x - 16384) * 2 + w;   // 0..1023
        int bh = unit >> 6, ch = unit & 63;
        int b = bh >> 3, h = bh & 7;
        int d = lane;
        const float* vp = V + ((((long)b * L_ + (long)ch * CHV) * H_ + h) << 6) + d;
        float ssum = 0.f;
#pragma unroll
        for (int ib = 0; ib < CHV; ib += 16) {
            float vb[16];
#pragma unroll
            for (int j = 0; j < 16; ++j) vb[j] = vp[(long)(ib + j) * (H_ * D_)];
#pragma unroll
            for (int j = 0; j < 16; ++j) ssum += vb[j];
        }
        ws[OFF_VSUM + unit * 64 + d] = ssum;
    }
}

// ---------------------------------------------------------------------------
// Kernel B: part 1 (blocks < 16): top-45 of M per (b,h) (iterative argmax,
//           lowest-index tie-break to match jax.lax.top_k)
//           part 2 (blocks >= 16): cumsum write, 16 loads in flight
// ---------------------------------------------------------------------------
__global__ __launch_bounds__(256) void kB(const float* __restrict__ V,
                                          float* __restrict__ out,
                                          float* __restrict__ ws)
{
    int tid = threadIdx.x;

    if (blockIdx.x < 16) {
        int bh = blockIdx.x;
        const float* M = ws + OFF_M + (long)bh * L_;
        int* Mtop = (int*)ws + OFF_MTOP + bh * NT_;

        float vals[16];
#pragma unroll
        for (int j = 0; j < 16; ++j) vals[j] = M[tid * 16 + j];
        float lv = NEG_BIG; int li = tid * 16;
#pragma unroll
        for (int j = 0; j < 16; ++j) {
            if (vals[j] > lv) { lv = vals[j]; li = tid * 16 + j; }
        }

        __shared__ float wbv[4];
        __shared__ int   wbi[4];
        int lane = tid & 63, w = tid >> 6;

        for (int r = 0; r < NT_; ++r) {
            float v = lv; int i = li;
#pragma unroll
            for (int off = 32; off; off >>= 1) {
                float v2 = __shfl_xor(v, off);
                int   i2 = __shfl_xor(i, off);
                if (v2 > v || (v2 == v && i2 < i)) { v = v2; i = i2; }
            }
            if (lane == 0) { wbv[w] = v; wbi[w] = i; }
            __syncthreads();
            float bv = wbv[0]; int bi = wbi[0];
#pragma unroll
            for (int g = 1; g < 4; ++g) {
                float v2 = wbv[g]; int i2 = wbi[g];
                if (v2 > bv || (v2 == bv && i2 < bi)) { bv = v2; bi = i2; }
            }
            if (tid == 0) Mtop[r] = bi;
            if ((bi >> 4) == tid) {
#pragma unroll
                for (int j = 0; j < 16; ++j)
                    if (j == (bi & 15)) vals[j] = NEG_BIG;
                lv = NEG_BIG; li = tid * 16;
#pragma unroll
                for (int j = 0; j < 16; ++j)
                    if (vals[j] > lv) { lv = vals[j]; li = tid * 16 + j; }
            }
            __syncthreads();
        }
    } else {
        // wave per (bh, ch): inclusive scan within chunk, offset from vsum
        int w = tid >> 6, d = tid & 63;
        int unit = (blockIdx.x - 16) * 4 + w;    // 0..1023
        int bh = unit >> 6, ch = unit & 63;
        int b = bh >> 3, h = bh & 7;

        // prefix over earlier chunk sums, 8 loads in flight
        float acc = 0.f;
        {
            const float* vs = ws + OFF_VSUM + (long)bh * NCHV * 64 + d;
            int c = 0;
            for (; c + 8 <= ch; c += 8) {
                float vb[8];
#pragma unroll
                for (int j = 0; j < 8; ++j) vb[j] = vs[(c + j) * 64];
#pragma unroll
                for (int j = 0; j < 8; ++j) acc += vb[j];
            }
            for (; c < ch; ++c) acc += vs[c * 64];
        }

        const float* vp = V   + ((((long)b * L_ + (long)ch * CHV) * H_ + h) << 6) + d;
        float*       op = out + ((((long)b * L_ + (long)ch * CHV) * H_ + h) << 6) + d;
#pragma unroll
        for (int ib = 0; ib < CHV; ib += 16) {
            float vb[16];
#pragma unroll
            for (int j = 0; j < 16; ++j) vb[j] = vp[(long)(ib + j) * (H_ * D_)];
#pragma unroll
            for (int j = 0; j < 16; ++j) {
                acc += vb[j];
                op[(long)(ib + j) * (H_ * D_)] = acc;
            }
        }
    }
}

// ---------------------------------------------------------------------------
// Kernel C: attention partials. Block = (bh, kc): 45 selected queries vs one
// 128-key chunk. K chunk staged coalesced into padded LDS (stride 68 floats:
// float4 reads land on the baseline b128 bank distribution -> no extra
// conflict); V read from global (coalesced, L1-resident); P in LDS.
// Static LDS = 34816 + 23040 + 192 = 58 KB -> 2 blocks/CU.
// ---------------------------------------------------------------------------
#define KPAD 68
__global__ __launch_bounds__(256) void kC(const float* __restrict__ Q,
                                          const float* __restrict__ Kt,
                                          const float* __restrict__ V,
                                          float* __restrict__ ws)
{
    __shared__ float Klds[KC * KPAD];  // 34816 B
    __shared__ float P[NT_ * KC];      // 23040 B (scores -> exp weights)
    __shared__ int   qpos[NT_];

    int tid = threadIdx.x;
    int bh = blockIdx.x >> 5, kc = blockIdx.x & 31;
    int b = bh >> 3, h = bh & 7;
    int kbase = kc * KC;

    if (tid < NT_) qpos[tid] = ((const int*)ws)[OFF_MTOP + bh * NT_ + tid];

    // coalesced K-chunk staging: 4 rows x 256B per iteration
    {
        const float* ksrc = Kt + ((((long)b * L_ + kbase) * H_ + h) << 6);
#pragma unroll
        for (int i = 0; i < 32; ++i) {
            int e = i * 256 + tid;
            int r = e >> 6, d = e & 63;
            Klds[r * KPAD + d] = ksrc[(long)r * (H_ * D_) + d];
        }
    }
    __syncthreads();

    // QK: thread = (k, u-half); K row from LDS into 64 VGPRs (one-time),
    // Q rows broadcast from global (L1). Fixed 23-trip per half (u=22 dup:
    // benign identical double-write).
    int k = tid & 127, uh = tid >> 7;
    int kpos = kbase + k;
    {
        float4 krow[16];
#pragma unroll
        for (int j = 0; j < 16; ++j)
            krow[j] = *(const float4*)&Klds[k * KPAD + j * 4];

#pragma unroll 2
        for (int j = 0; j < 23; ++j) {
            int u = uh * 22 + j;
            int qp_ = qpos[u];
            const float4* qrow = (const float4*)(Q + ((((long)b * L_ + qp_) * H_ + h) << 6));
            float acc = 0.f;
#pragma unroll
            for (int jj = 0; jj < 16; ++jj) {
                float4 qv = qrow[jj];
                acc += qv.x * krow[jj].x + qv.y * krow[jj].y +
                       qv.z * krow[jj].z + qv.w * krow[jj].w;
            }
            float sc = acc * SCALE;
            if (kpos > qp_) sc = NEG_BIG;   // causal mask
            P[u * KC + k] = sc;
        }
    }
    __syncthreads();

    // per-u softmax partials (wave w handles u = w, w+4, ...)
    int lane = tid & 63, w = tid >> 6;
    for (int u = w; u < NT_; u += 4) {
        float s0 = P[u * KC + lane];
        float s1 = P[u * KC + 64 + lane];
        float m = fmaxf(s0, s1);
#pragma unroll
        for (int off = 32; off; off >>= 1) m = fmaxf(m, __shfl_xor(m, off));
        float e0 = __expf(s0 - m), e1 = __expf(s1 - m);
        P[u * KC + lane]      = e0;
        P[u * KC + 64 + lane] = e1;
        float sm = e0 + e1;
#pragma unroll
        for (int off = 32; off; off >>= 1) sm += __shfl_xor(sm, off);
        if (lane == 0) {
            ws[OFF_MPART + ((long)bh * NT_ + u) * NKC + kc] = m;
            ws[OFF_SPART + ((long)bh * NT_ + u) * NKC + kc] = sm;
        }
    }
    __syncthreads();

    // PV: wave w accumulates ctx for u in {w, w+4, ...}; lane = d.
    // V from global (coalesced 256B/instr, L1-hit); P broadcast float4.
    {
        const float* vsrc = V + ((((long)b * L_ + kbase) * H_ + h) << 6);
        float ctx[12];
#pragma unroll
        for (int j = 0; j < 12; ++j) ctx[j] = 0.f;
        for (int kk = 0; kk < KC; kk += 4) {
            float v0 = vsrc[(long)(kk + 0) * (H_ * D_) + lane];
            float v1 = vsrc[(long)(kk + 1) * (H_ * D_) + lane];
            float v2 = vsrc[(long)(kk + 2) * (H_ * D_) + lane];
            float v3 = vsrc[(long)(kk + 3) * (H_ * D_) + lane];
#pragma unroll
            for (int j = 0; j < 12; ++j) {
                int u = w + j * 4;
                if (u < NT_) {
                    float4 pv = *(const float4*)&P[u * KC + kk];  // broadcast
                    ctx[j] += pv.x * v0 + pv.y * v1 + pv.z * v2 + pv.w * v3;
                }
            }
        }
#pragma unroll
        for (int j = 0; j < 12; ++j) {
            int u = w + j * 4;
            if (u < NT_)
                ws[OFF_CTXP + ((long)(bh * NKC + kc) * NT_ + u) * 64 + lane] = ctx[j];
        }
    }
}

// ---------------------------------------------------------------------------
// Kernel D: merge chunk partials (log-sum-exp) and overwrite selected rows.
// MPART/SPART are [bh][u][kc] -> float4 merge loads.
// ---------------------------------------------------------------------------
__global__ __launch_bounds__(256) void kD(float* __restrict__ out,
                                          const float* __restrict__ ws)
{
    int tid  = threadIdx.x;
    int w    = tid >> 6;
    int lane = tid & 63;
    int unit = blockIdx.x * 4 + w;       // 0..719
    if (unit >= BH_ * NT_) return;
    int bh = unit / NT_, u = unit - bh * NT_;
    int b = bh >> 3, h = bh & 7;

    const float4* mp4 = (const float4*)(ws + OFF_MPART + ((long)bh * NT_ + u) * NKC);
    const float4* sp4 = (const float4*)(ws + OFF_SPART + ((long)bh * NT_ + u) * NKC);

    float mc[NKC], sc[NKC];
    float m = NEG_BIG;
#pragma unroll
    for (int c4 = 0; c4 < NKC / 4; ++c4) {
        float4 mv = mp4[c4];
        float4 sv = sp4[c4];
        mc[c4 * 4 + 0] = mv.x; mc[c4 * 4 + 1] = mv.y;
        mc[c4 * 4 + 2] = mv.z; mc[c4 * 4 + 3] = mv.w;
        sc[c4 * 4 + 0] = sv.x; sc[c4 * 4 + 1] = sv.y;
        sc[c4 * 4 + 2] = sv.z; sc[c4 * 4 + 3] = sv.w;
        m = fmaxf(m, fmaxf(fmaxf(mv.x, mv.y), fmaxf(mv.z, mv.w)));
    }
    float T = 0.f, ctx = 0.f;
#pragma unroll
    for (int c = 0; c < NKC; ++c) {
        float wgt = __expf(mc[c] - m);   // fully-masked chunks: exp(-1e30-m) = 0
        T   += sc[c] * wgt;
        ctx += ws[OFF_CTXP + ((long)(bh * NKC + c) * NT_ + u) * 64 + lane] * wgt;
    }
    int qp = ((const int*)ws)[OFF_MTOP + bh * NT_ + u];
    out[((((long)b * L_ + qp) * H_ + h) << 6) + lane] = ctx / T;
}

// ---------------------------------------------------------------------------
extern "C" void kernel_launch(void* const* d_in, const int* in_sizes, int n_in,
                              void* d_out, int out_size, void* d_ws, size_t ws_size,
                              hipStream_t stream)
{
    const float* Q    = (const float*)d_in[0];
    const float* K    = (const float*)d_in[1];
    const float* V    = (const float*)d_in[2];
    const int*   samp = (const int*)d_in[4];   // d_in[3] = attn_mask (unused)
    float* out = (float*)d_out;
    float* ws  = (float*)d_ws;

    // A: M scores (16384 blocks = (b,q,hh), XCD-slab swizzled) + V chunk
    //    sums (512 blocks x 2 waves)
    kA<<<16896, 128, 0, stream>>>(Q, K, V, samp, ws);
    // B: top-45 (16 blocks) + cumsum write (256 blocks)
    kB<<<272, 256, 0, stream>>>(V, out, ws);
    // C: attention partials (16 bh x 32 key chunks)
    kC<<<512, 256, 0, stream>>>(Q, K, V, ws);
    // D: merge + scatter selected rows (720 waves)
    kD<<<180, 256, 0, stream>>>(out, ws);
}